// Round 1
// baseline (1347.203 us; speedup 1.0000x reference)
//
#include <hip/hip_runtime.h>
#include <hip/hip_bf16.h>

#define SEQ   80
#define BATCH 32768
#define HID   10

typedef unsigned int uint;
typedef unsigned short ushort;

__device__ __forceinline__ float fast_sig(float x) {
    // 1/(1+exp(-x)) via v_exp_f32 (2^y) + v_rcp_f32
    return __builtin_amdgcn_rcpf(1.0f + __builtin_amdgcn_exp2f(-1.44269504f * x));
}
__device__ __forceinline__ float fast_tanh(float x) {
    // tanh(x) = 2/(1+exp(-2x)) - 1
    return 2.0f * __builtin_amdgcn_rcpf(1.0f + __builtin_amdgcn_exp2f(-2.88539008f * x)) - 1.0f;
}

__device__ __forceinline__ ushort bf16bits(float v) {
    __hip_bfloat16 h = __float2bfloat16(v);
    return *reinterpret_cast<ushort*>(&h);
}

__global__ __launch_bounds__(64)
void lstm2_kernel(const float* __restrict__ x,
                  const float* __restrict__ h0in, const float* __restrict__ c0in,
                  const float* __restrict__ Wih0, const float* __restrict__ Whh0,
                  const float* __restrict__ bih0, const float* __restrict__ bhh0,
                  const float* __restrict__ Wih1, const float* __restrict__ Whh1,
                  const float* __restrict__ bih1, const float* __restrict__ bhh1,
                  ushort* __restrict__ y /* bf16 bits, flat [T,B,H] */) {
    const int b = blockIdx.x * blockDim.x + threadIdx.x;
    if (b >= BATCH) return;

    float h0[HID], c0[HID], h1[HID], c1[HID];
#pragma unroll
    for (int j = 0; j < HID; ++j) {
        h0[j] = h0in[(size_t)b * HID + j];
        c0[j] = c0in[(size_t)b * HID + j];
        h1[j] = h0in[(size_t)BATCH * HID + (size_t)b * HID + j];
        c1[j] = c0in[(size_t)BATCH * HID + (size_t)b * HID + j];
    }

    for (int t = 0; t < SEQ; ++t) {
        const float2 xv = *reinterpret_cast<const float2*>(&x[((size_t)t * BATCH + b) * 2]);
        float hn[HID];

        // ----- layer 0: gates = x @ Wih0.T + h0 @ Whh0.T + b -----
#pragma unroll
        for (int j = 0; j < HID; ++j) {
            float ai = bih0[j]      + bhh0[j]      + Wih0[(j)*2]*xv.x      + Wih0[(j)*2+1]*xv.y;
            float af = bih0[j+10]   + bhh0[j+10]   + Wih0[(j+10)*2]*xv.x   + Wih0[(j+10)*2+1]*xv.y;
            float ag = bih0[j+20]   + bhh0[j+20]   + Wih0[(j+20)*2]*xv.x   + Wih0[(j+20)*2+1]*xv.y;
            float ao = bih0[j+30]   + bhh0[j+30]   + Wih0[(j+30)*2]*xv.x   + Wih0[(j+30)*2+1]*xv.y;
#pragma unroll
            for (int k = 0; k < HID; ++k) {
                ai += Whh0[(j)*10+k]    * h0[k];
                af += Whh0[(j+10)*10+k] * h0[k];
                ag += Whh0[(j+20)*10+k] * h0[k];
                ao += Whh0[(j+30)*10+k] * h0[k];
            }
            const float ii = fast_sig(ai);
            const float ff = fast_sig(af);
            const float gg = fast_tanh(ag);
            const float oo = fast_sig(ao);
            const float c  = ff * c0[j] + ii * gg;
            c0[j] = c;
            hn[j] = oo * fast_tanh(c);
        }
#pragma unroll
        for (int j = 0; j < HID; ++j) h0[j] = hn[j];

        // ----- layer 1: gates = h0(new) @ Wih1.T + h1 @ Whh1.T + b -----
#pragma unroll
        for (int j = 0; j < HID; ++j) {
            float ai = bih1[j]    + bhh1[j];
            float af = bih1[j+10] + bhh1[j+10];
            float ag = bih1[j+20] + bhh1[j+20];
            float ao = bih1[j+30] + bhh1[j+30];
#pragma unroll
            for (int k = 0; k < HID; ++k) {
                ai += Wih1[(j)*10+k]    * h0[k] + Whh1[(j)*10+k]    * h1[k];
                af += Wih1[(j+10)*10+k] * h0[k] + Whh1[(j+10)*10+k] * h1[k];
                ag += Wih1[(j+20)*10+k] * h0[k] + Whh1[(j+20)*10+k] * h1[k];
                ao += Wih1[(j+30)*10+k] * h0[k] + Whh1[(j+30)*10+k] * h1[k];
            }
            const float ii = fast_sig(ai);
            const float ff = fast_sig(af);
            const float gg = fast_tanh(ag);
            const float oo = fast_sig(ao);
            const float c  = ff * c1[j] + ii * gg;
            c1[j] = c;
            hn[j] = oo * fast_tanh(c);
        }
#pragma unroll
        for (int j = 0; j < HID; ++j) h1[j] = hn[j];

        // ----- store tanh(h1) as bf16, flat [T,B,H] -----
        uint p[5];
#pragma unroll
        for (int jj = 0; jj < 5; ++jj) {
            const ushort lo = bf16bits(fast_tanh(h1[2*jj]));
            const ushort hi = bf16bits(fast_tanh(h1[2*jj+1]));
            p[jj] = (uint)lo | ((uint)hi << 16);
        }
        uint* yp = reinterpret_cast<uint*>(y + ((size_t)t * BATCH + b) * HID);
#pragma unroll
        for (int jj = 0; jj < 5; ++jj) yp[jj] = p[jj];
    }
}

// Head: row b of tanh(y1).view(B,-1) is the contiguous flat range [b*800, (b+1)*800)
__global__ __launch_bounds__(64)
void head_kernel(const ushort* __restrict__ yflat, /* bf16 bits, 80*32768*10 */
                 const float* __restrict__ W1, const float* __restrict__ b1,
                 const float* __restrict__ W2, const float* __restrict__ b2,
                 float* __restrict__ out) {
    const int b = blockIdx.x * blockDim.x + threadIdx.x;
    if (b >= BATCH) return;

    const ushort* yr = yflat + (size_t)b * 800;
    float acc[10];
#pragma unroll
    for (int o = 0; o < 10; ++o) acc[o] = b1[o];

    for (int k0 = 0; k0 < 800; k0 += 8) {
        const uint4 q = *reinterpret_cast<const uint4*>(yr + k0);  // 16B aligned: b*1600 + k0*2
        float yv[8];
        yv[0] = __uint_as_float(q.x << 16); yv[1] = __uint_as_float(q.x & 0xffff0000u);
        yv[2] = __uint_as_float(q.y << 16); yv[3] = __uint_as_float(q.y & 0xffff0000u);
        yv[4] = __uint_as_float(q.z << 16); yv[5] = __uint_as_float(q.z & 0xffff0000u);
        yv[6] = __uint_as_float(q.w << 16); yv[7] = __uint_as_float(q.w & 0xffff0000u);
#pragma unroll
        for (int u = 0; u < 8; ++u) {
#pragma unroll
            for (int o = 0; o < 10; ++o) {
                acc[o] += yv[u] * W1[o * 800 + k0 + u];
            }
        }
    }

    float s[10];
#pragma unroll
    for (int o = 0; o < 10; ++o) s[o] = fast_sig(acc[o]);

#pragma unroll
    for (int j = 0; j < 40; ++j) {
        float r = b2[j];
#pragma unroll
        for (int o = 0; o < 10; ++o) r += s[o] * W2[j * 10 + o];
        out[(size_t)b * 40 + j] = r;
    }
}

extern "C" void kernel_launch(void* const* d_in, const int* in_sizes, int n_in,
                              void* d_out, int out_size, void* d_ws, size_t ws_size,
                              hipStream_t stream) {
    const float* x    = (const float*)d_in[0];
    const float* h0   = (const float*)d_in[1];
    const float* c0   = (const float*)d_in[2];
    const float* Wih0 = (const float*)d_in[3];
    const float* Whh0 = (const float*)d_in[4];
    const float* bih0 = (const float*)d_in[5];
    const float* bhh0 = (const float*)d_in[6];
    const float* Wih1 = (const float*)d_in[7];
    const float* Whh1 = (const float*)d_in[8];
    const float* bih1 = (const float*)d_in[9];
    const float* bhh1 = (const float*)d_in[10];
    const float* W1   = (const float*)d_in[11];
    const float* b1   = (const float*)d_in[12];
    const float* W2   = (const float*)d_in[13];
    const float* b2   = (const float*)d_in[14];
    float* out = (float*)d_out;
    ushort* yws = (ushort*)d_ws;  // bf16 staging, 80*32768*10*2 = 52,428,800 bytes

    lstm2_kernel<<<BATCH / 64, 64, 0, stream>>>(x, h0, c0, Wih0, Whh0, bih0, bhh0,
                                                Wih1, Whh1, bih1, bhh1, yws);
    head_kernel<<<BATCH / 64, 64, 0, stream>>>(yws, W1, b1, W2, b2, out);
}

// Round 2
// 331.595 us; speedup vs baseline: 4.0628x; 4.0628x over previous
//
#include <hip/hip_runtime.h>
#include <hip/hip_bf16.h>

#define SEQ   80
#define BATCH 32768
#define HID   10

typedef unsigned int uint;
typedef unsigned short ushort;

__device__ __forceinline__ float fast_sig(float x) {
    return __builtin_amdgcn_rcpf(1.0f + __builtin_amdgcn_exp2f(-1.44269504f * x));
}
__device__ __forceinline__ float fast_tanh(float x) {
    return 2.0f * __builtin_amdgcn_rcpf(1.0f + __builtin_amdgcn_exp2f(-2.88539008f * x)) - 1.0f;
}
__device__ __forceinline__ ushort bf16bits(float v) {
    __hip_bfloat16 h = __float2bfloat16(v);
    return *reinterpret_cast<ushort*>(&h);
}

// One hidden unit per lane; 10 lanes per batch element; 6 elements per wave64
// (lanes 60-63 idle). All weights for a lane's unit (136 floats) live in VGPRs
// for the whole kernel; the recurrent step touches global memory only for the
// 8-byte x-load and the 2-byte y-store. h broadcast among the 10 unit-lanes of
// an element via __shfl (ds_bpermute).
__global__ __launch_bounds__(256)
void lstm2_kernel(const float* __restrict__ x,
                  const float* __restrict__ h0in, const float* __restrict__ c0in,
                  const float* __restrict__ Wih0, const float* __restrict__ Whh0,
                  const float* __restrict__ bih0, const float* __restrict__ bhh0,
                  const float* __restrict__ Wih1, const float* __restrict__ Whh1,
                  const float* __restrict__ bih1, const float* __restrict__ bhh1,
                  ushort* __restrict__ y /* bf16 bits, flat [T,B,H] */) {
    const int l     = threadIdx.x & 63;          // lane in wave
    const int wv    = threadIdx.x >> 6;          // wave in block (0..3)
    const int e_loc = l / 10;                    // 0..5 real, 6 = idle lanes
    const int u     = l - e_loc * 10;            // unit 0..9
    const long b    = (long)blockIdx.x * 24 + wv * 6 + e_loc;
    const bool unit_ok = (e_loc < 6);
    const bool active  = unit_ok && (b < BATCH);
    const int shfl_base = e_loc * 10;            // src lane base for h broadcast

    // ---- per-lane weight registers: rows {u, u+10, u+20, u+30} ----
    float wih0[4][2], whh0[4][10], bias0[4];
    float wih1[4][10], whh1[4][10], bias1[4];
#pragma unroll
    for (int g = 0; g < 4; ++g) {
        const int r = u + 10 * g;
        if (unit_ok) {
            wih0[g][0] = Wih0[r * 2];
            wih0[g][1] = Wih0[r * 2 + 1];
            bias0[g]   = bih0[r] + bhh0[r];
            bias1[g]   = bih1[r] + bhh1[r];
#pragma unroll
            for (int k = 0; k < 10; ++k) {
                whh0[g][k] = Whh0[r * 10 + k];
                wih1[g][k] = Wih1[r * 10 + k];
                whh1[g][k] = Whh1[r * 10 + k];
            }
        } else {
            wih0[g][0] = wih0[g][1] = 0.f; bias0[g] = 0.f; bias1[g] = 0.f;
#pragma unroll
            for (int k = 0; k < 10; ++k) { whh0[g][k] = 0.f; wih1[g][k] = 0.f; whh1[g][k] = 0.f; }
        }
    }

    // ---- state ----
    float h0b[10], h1b[10], c0r, c1r;
    if (active) {
#pragma unroll
        for (int k = 0; k < 10; ++k) {
            h0b[k] = h0in[b * 10 + k];
            h1b[k] = h0in[(size_t)BATCH * 10 + b * 10 + k];
        }
        c0r = c0in[b * 10 + u];
        c1r = c0in[(size_t)BATCH * 10 + b * 10 + u];
    } else {
#pragma unroll
        for (int k = 0; k < 10; ++k) { h0b[k] = 0.f; h1b[k] = 0.f; }
        c0r = 0.f; c1r = 0.f;
    }

    // prefetched x
    float2 xv = active ? *reinterpret_cast<const float2*>(&x[b * 2]) : make_float2(0.f, 0.f);

    for (int t = 0; t < SEQ; ++t) {
        // prefetch next step's x while we compute
        const int tn = (t + 1 < SEQ) ? (t + 1) : t;
        float2 xnext = active ? *reinterpret_cast<const float2*>(&x[((size_t)tn * BATCH + b) * 2])
                              : make_float2(0.f, 0.f);

        // ----- layer 0 -----
        float a[4];
#pragma unroll
        for (int g = 0; g < 4; ++g)
            a[g] = bias0[g] + wih0[g][0] * xv.x + wih0[g][1] * xv.y;
#pragma unroll
        for (int k = 0; k < 10; ++k) {
#pragma unroll
            for (int g = 0; g < 4; ++g) a[g] += whh0[g][k] * h0b[k];
        }
        {
            const float ii = fast_sig(a[0]);
            const float ff = fast_sig(a[1]);
            const float gg = fast_tanh(a[2]);
            const float oo = fast_sig(a[3]);
            c0r = ff * c0r + ii * gg;
        }
        const float h0n = /*oo*/ fast_sig(a[3]) * fast_tanh(c0r);
#pragma unroll
        for (int k = 0; k < 10; ++k) h0b[k] = __shfl(h0n, shfl_base + k, 64);

        // ----- layer 1 -----
#pragma unroll
        for (int g = 0; g < 4; ++g) a[g] = bias1[g];
#pragma unroll
        for (int k = 0; k < 10; ++k) {
#pragma unroll
            for (int g = 0; g < 4; ++g)
                a[g] += wih1[g][k] * h0b[k] + whh1[g][k] * h1b[k];
        }
        const float ii1 = fast_sig(a[0]);
        const float ff1 = fast_sig(a[1]);
        const float gg1 = fast_tanh(a[2]);
        const float oo1 = fast_sig(a[3]);
        c1r = ff1 * c1r + ii1 * gg1;
        const float h1n = oo1 * fast_tanh(c1r);
#pragma unroll
        for (int k = 0; k < 10; ++k) h1b[k] = __shfl(h1n, shfl_base + k, 64);

        if (active) y[(size_t)t * BATCH * HID + b * 10 + u] = bf16bits(fast_tanh(h1n));
        xv = xnext;
    }
}

// Head: row b of tanh(y1).view(B,-1) is the contiguous flat range [b*800,(b+1)*800).
// 4 lanes per row, each dotting 200 contiguous bf16 elements, butterfly-reduced.
__global__ __launch_bounds__(256)
void head_kernel(const ushort* __restrict__ yflat, /* bf16 bits, 80*32768*10 */
                 const float* __restrict__ W1, const float* __restrict__ b1,
                 const float* __restrict__ W2, const float* __restrict__ b2,
                 float* __restrict__ out) {
    const int tid = blockIdx.x * blockDim.x + threadIdx.x;
    const int row = tid >> 2;
    const int sub = tid & 3;
    if (row >= BATCH) return;

    const ushort* yr = yflat + (size_t)row * 800 + sub * 200;
    const int kbase = sub * 200;
    float acc[10];
#pragma unroll
    for (int o = 0; o < 10; ++o) acc[o] = 0.f;

    for (int k0 = 0; k0 < 200; k0 += 8) {
        const uint4 q = *reinterpret_cast<const uint4*>(yr + k0);  // 16B aligned
        float yv[8];
        yv[0] = __uint_as_float(q.x << 16); yv[1] = __uint_as_float(q.x & 0xffff0000u);
        yv[2] = __uint_as_float(q.y << 16); yv[3] = __uint_as_float(q.y & 0xffff0000u);
        yv[4] = __uint_as_float(q.z << 16); yv[5] = __uint_as_float(q.z & 0xffff0000u);
        yv[6] = __uint_as_float(q.w << 16); yv[7] = __uint_as_float(q.w & 0xffff0000u);
#pragma unroll
        for (int u = 0; u < 8; ++u) {
#pragma unroll
            for (int o = 0; o < 10; ++o) acc[o] += yv[u] * W1[o * 800 + kbase + k0 + u];
        }
    }

    // butterfly reduce across the 4 sub-lanes
#pragma unroll
    for (int o = 0; o < 10; ++o) {
        acc[o] += __shfl_xor(acc[o], 1, 64);
        acc[o] += __shfl_xor(acc[o], 2, 64);
    }

    float s[10];
#pragma unroll
    for (int o = 0; o < 10; ++o) s[o] = fast_sig(acc[o] + b1[o]);

    // each sub-lane produces 10 of the 40 outputs
    const int jbase = sub * 10;
#pragma unroll
    for (int jj = 0; jj < 10; ++jj) {
        const int j = jbase + jj;
        float r = b2[j];
#pragma unroll
        for (int o = 0; o < 10; ++o) r += s[o] * W2[j * 10 + o];
        out[(size_t)row * 40 + j] = r;
    }
}

extern "C" void kernel_launch(void* const* d_in, const int* in_sizes, int n_in,
                              void* d_out, int out_size, void* d_ws, size_t ws_size,
                              hipStream_t stream) {
    const float* x    = (const float*)d_in[0];
    const float* h0   = (const float*)d_in[1];
    const float* c0   = (const float*)d_in[2];
    const float* Wih0 = (const float*)d_in[3];
    const float* Whh0 = (const float*)d_in[4];
    const float* bih0 = (const float*)d_in[5];
    const float* bhh0 = (const float*)d_in[6];
    const float* Wih1 = (const float*)d_in[7];
    const float* Whh1 = (const float*)d_in[8];
    const float* bih1 = (const float*)d_in[9];
    const float* bhh1 = (const float*)d_in[10];
    const float* W1   = (const float*)d_in[11];
    const float* b1   = (const float*)d_in[12];
    const float* W2   = (const float*)d_in[13];
    const float* b2   = (const float*)d_in[14];
    float* out = (float*)d_out;
    ushort* yws = (ushort*)d_ws;  // bf16 staging, 80*32768*10*2 = 52,428,800 bytes

    // 24 batch elements per 256-thread block (6 per wave64)
    const int grid_lstm = (BATCH + 23) / 24;   // 1366
    lstm2_kernel<<<grid_lstm, 256, 0, stream>>>(x, h0, c0, Wih0, Whh0, bih0, bhh0,
                                                Wih1, Whh1, bih1, bhh1, yws);
    // 4 lanes per row
    head_kernel<<<(BATCH * 4) / 256, 256, 0, stream>>>(yws, W1, b1, W2, b2, out);
}

// Round 3
// 307.003 us; speedup vs baseline: 4.3882x; 1.0801x over previous
//
#include <hip/hip_runtime.h>
#include <hip/hip_bf16.h>

#define SEQ   80
#define BATCH 32768
#define HID   10

typedef unsigned int uint;
typedef unsigned short ushort;

__device__ __forceinline__ float fast_sig(float x) {
    return __builtin_amdgcn_rcpf(1.0f + __builtin_amdgcn_exp2f(-1.44269504f * x));
}
__device__ __forceinline__ float fast_tanh(float x) {
    return 2.0f * __builtin_amdgcn_rcpf(1.0f + __builtin_amdgcn_exp2f(-2.88539008f * x)) - 1.0f;
}
__device__ __forceinline__ ushort bf16bits(float v) {
    __hip_bfloat16 h = __float2bfloat16(v);
    return *reinterpret_cast<ushort*>(&h);
}

// One hidden unit per lane; 10 lanes per batch element; 6 elements per wave64.
// __launch_bounds__(64,2): VGPR cap 256 so the 136 weight floats per lane stay
// register-resident (round-2's launch_bounds(256) made the compiler target 5
// waves/SIMD -> VGPR=92 -> weight reloads inside the t-loop, 2x slowdown).
__global__ __launch_bounds__(64, 2)
void lstm2_kernel(const float* __restrict__ x,
                  const float* __restrict__ h0in, const float* __restrict__ c0in,
                  const float* __restrict__ Wih0, const float* __restrict__ Whh0,
                  const float* __restrict__ bih0, const float* __restrict__ bhh0,
                  const float* __restrict__ Wih1, const float* __restrict__ Whh1,
                  const float* __restrict__ bih1, const float* __restrict__ bhh1,
                  ushort* __restrict__ y /* bf16 bits, flat [T,B,H] */) {
    const int l     = threadIdx.x;               // 0..63
    const int e_loc = l / 10;                    // 0..5 real, 6 = lanes 60-63
    const int u     = l - e_loc * 10;            // unit 0..9 (0..3 for e_loc==6)
    const long b    = (long)blockIdx.x * 6 + e_loc;
    const bool active = (e_loc < 6) && (b < BATCH);
    const long b_eff  = (b < BATCH) ? b : (BATCH - 1);   // clamp for loads
    const int shfl_base = e_loc * 10;

    // ---- per-lane weight registers: rows {u, u+10, u+20, u+30} ----
    // All lanes load real rows (u<=9 always) -> no divergence at init.
    float wih0[4][2], whh0[4][10], bias0[4];
    float wih1[4][10], whh1[4][10], bias1[4];
#pragma unroll
    for (int g = 0; g < 4; ++g) {
        const int r = u + 10 * g;
        wih0[g][0] = Wih0[r * 2];
        wih0[g][1] = Wih0[r * 2 + 1];
        bias0[g]   = bih0[r] + bhh0[r];
        bias1[g]   = bih1[r] + bhh1[r];
#pragma unroll
        for (int k = 0; k < 10; ++k) {
            whh0[g][k] = Whh0[r * 10 + k];
            wih1[g][k] = Wih1[r * 10 + k];
            whh1[g][k] = Whh1[r * 10 + k];
        }
    }

    // ---- state (loads clamped, stores guarded) ----
    float h0b[10], h1b[10], c0r, c1r;
#pragma unroll
    for (int k = 0; k < 10; ++k) {
        h0b[k] = h0in[b_eff * 10 + k];
        h1b[k] = h0in[(size_t)BATCH * 10 + b_eff * 10 + k];
    }
    c0r = c0in[b_eff * 10 + u];
    c1r = c0in[(size_t)BATCH * 10 + b_eff * 10 + u];

    float2 xv = *reinterpret_cast<const float2*>(&x[b_eff * 2]);

    for (int t = 0; t < SEQ; ++t) {
        const int tn = (t + 1 < SEQ) ? (t + 1) : t;
        const float2 xnext = *reinterpret_cast<const float2*>(&x[((size_t)tn * BATCH + b_eff) * 2]);

        // ----- layer 0 -----
        float a[4];
#pragma unroll
        for (int g = 0; g < 4; ++g)
            a[g] = bias0[g] + wih0[g][0] * xv.x + wih0[g][1] * xv.y;
#pragma unroll
        for (int k = 0; k < 10; ++k) {
#pragma unroll
            for (int g = 0; g < 4; ++g) a[g] += whh0[g][k] * h0b[k];
        }
        const float i0 = fast_sig(a[0]);
        const float f0 = fast_sig(a[1]);
        const float g0 = fast_tanh(a[2]);
        const float o0 = fast_sig(a[3]);
        c0r = f0 * c0r + i0 * g0;
        const float h0n = o0 * fast_tanh(c0r);
#pragma unroll
        for (int k = 0; k < 10; ++k) h0b[k] = __shfl(h0n, shfl_base + k, 64);

        // ----- layer 1 -----
#pragma unroll
        for (int g = 0; g < 4; ++g) a[g] = bias1[g];
#pragma unroll
        for (int k = 0; k < 10; ++k) {
#pragma unroll
            for (int g = 0; g < 4; ++g)
                a[g] += wih1[g][k] * h0b[k] + whh1[g][k] * h1b[k];
        }
        const float i1 = fast_sig(a[0]);
        const float f1 = fast_sig(a[1]);
        const float g1 = fast_tanh(a[2]);
        const float o1 = fast_sig(a[3]);
        c1r = f1 * c1r + i1 * g1;
        const float h1n = o1 * fast_tanh(c1r);
#pragma unroll
        for (int k = 0; k < 10; ++k) h1b[k] = __shfl(h1n, shfl_base + k, 64);

        if (active) y[(size_t)t * BATCH * HID + b * 10 + u] = bf16bits(fast_tanh(h1n));
        xv = xnext;
    }
}

// Head: row b of tanh(y1).view(B,-1) is the contiguous flat range [b*800,(b+1)*800).
// 4 lanes per row, each dotting 200 contiguous bf16 elements, butterfly-reduced.
__global__ __launch_bounds__(256)
void head_kernel(const ushort* __restrict__ yflat, /* bf16 bits, 80*32768*10 */
                 const float* __restrict__ W1, const float* __restrict__ b1,
                 const float* __restrict__ W2, const float* __restrict__ b2,
                 float* __restrict__ out) {
    const int tid = blockIdx.x * blockDim.x + threadIdx.x;
    const int row = tid >> 2;
    const int sub = tid & 3;
    if (row >= BATCH) return;

    const ushort* yr = yflat + (size_t)row * 800 + sub * 200;
    const int kbase = sub * 200;
    float acc[10];
#pragma unroll
    for (int o = 0; o < 10; ++o) acc[o] = 0.f;

#pragma unroll 2
    for (int k0 = 0; k0 < 200; k0 += 8) {
        const uint4 q = *reinterpret_cast<const uint4*>(yr + k0);  // 16B aligned
        float yv[8];
        yv[0] = __uint_as_float(q.x << 16); yv[1] = __uint_as_float(q.x & 0xffff0000u);
        yv[2] = __uint_as_float(q.y << 16); yv[3] = __uint_as_float(q.y & 0xffff0000u);
        yv[4] = __uint_as_float(q.z << 16); yv[5] = __uint_as_float(q.z & 0xffff0000u);
        yv[6] = __uint_as_float(q.w << 16); yv[7] = __uint_as_float(q.w & 0xffff0000u);
#pragma unroll
        for (int uu = 0; uu < 8; ++uu) {
#pragma unroll
            for (int o = 0; o < 10; ++o) acc[o] += yv[uu] * W1[o * 800 + kbase + k0 + uu];
        }
    }

    // butterfly reduce across the 4 sub-lanes
#pragma unroll
    for (int o = 0; o < 10; ++o) {
        acc[o] += __shfl_xor(acc[o], 1, 64);
        acc[o] += __shfl_xor(acc[o], 2, 64);
    }

    float s[10];
#pragma unroll
    for (int o = 0; o < 10; ++o) s[o] = fast_sig(acc[o] + b1[o]);

    // each sub-lane produces 10 of the 40 outputs
    const int jbase = sub * 10;
#pragma unroll
    for (int jj = 0; jj < 10; ++jj) {
        const int j = jbase + jj;
        float r = b2[j];
#pragma unroll
        for (int o = 0; o < 10; ++o) r += s[o] * W2[j * 10 + o];
        out[(size_t)row * 40 + j] = r;
    }
}

extern "C" void kernel_launch(void* const* d_in, const int* in_sizes, int n_in,
                              void* d_out, int out_size, void* d_ws, size_t ws_size,
                              hipStream_t stream) {
    const float* x    = (const float*)d_in[0];
    const float* h0   = (const float*)d_in[1];
    const float* c0   = (const float*)d_in[2];
    const float* Wih0 = (const float*)d_in[3];
    const float* Whh0 = (const float*)d_in[4];
    const float* bih0 = (const float*)d_in[5];
    const float* bhh0 = (const float*)d_in[6];
    const float* Wih1 = (const float*)d_in[7];
    const float* Whh1 = (const float*)d_in[8];
    const float* bih1 = (const float*)d_in[9];
    const float* bhh1 = (const float*)d_in[10];
    const float* W1   = (const float*)d_in[11];
    const float* b1   = (const float*)d_in[12];
    const float* W2   = (const float*)d_in[13];
    const float* b2   = (const float*)d_in[14];
    float* out = (float*)d_out;
    ushort* yws = (ushort*)d_ws;  // bf16 staging, 80*32768*10*2 = 52,428,800 bytes

    // 6 batch elements per 64-thread (1-wave) block
    const int grid_lstm = (BATCH + 5) / 6;   // 5462
    lstm2_kernel<<<grid_lstm, 64, 0, stream>>>(x, h0, c0, Wih0, Whh0, bih0, bhh0,
                                               Wih1, Whh1, bih1, bhh1, yws);
    head_kernel<<<(BATCH * 4) / 256, 256, 0, stream>>>(yws, W1, b1, W2, b2, out);
}

// Round 4
// 300.336 us; speedup vs baseline: 4.4857x; 1.0222x over previous
//
#include <hip/hip_runtime.h>
#include <hip/hip_bf16.h>

#define SEQ   80
#define BATCH 32768
#define HID   10

typedef unsigned int uint;
typedef unsigned short ushort;

// Pre-scaled nonlinearities: caller folds -log2(e) (sigmoid) or -2log2(e)
// (tanh) into the pre-activation via weight/bias scaling at init.
__device__ __forceinline__ float sig_pre(float a) {   // a = -1.4427*x
    return __builtin_amdgcn_rcpf(1.0f + __builtin_amdgcn_exp2f(a));
}
__device__ __forceinline__ float tanh_pre(float a) {  // a = -2.8854*x
    return 2.0f * __builtin_amdgcn_rcpf(1.0f + __builtin_amdgcn_exp2f(a)) - 1.0f;
}
__device__ __forceinline__ float fast_tanh(float x) {
    return 2.0f * __builtin_amdgcn_rcpf(1.0f + __builtin_amdgcn_exp2f(-2.88539008f * x)) - 1.0f;
}
__device__ __forceinline__ ushort bf16bits(float v) {
    __hip_bfloat16 h = __float2bfloat16(v);
    return *reinterpret_cast<ushort*>(&h);
}

#define SIG_SCALE  (-1.44269504f)
#define TANH_SCALE (-2.88539008f)

// One hidden unit per lane; 10 lanes per batch element; 6 elements per wave64.
// amdgpu_waves_per_eu(2,2): occupancy TARGET (not just floor) = 2 waves/EU ->
// 256-VGPR budget, so the 136 weight floats per lane can stay resident.
// asm pins after init make the weight loads non-rematerializable so the
// register allocator cannot sink them back into the t-loop (round-3 failure:
// VGPR=92, weights reloaded every step, FETCH 41.7MB).
__global__ __attribute__((amdgpu_flat_work_group_size(64, 64), amdgpu_waves_per_eu(2, 2)))
void lstm2_kernel(const float* __restrict__ x,
                  const float* __restrict__ h0in, const float* __restrict__ c0in,
                  const float* __restrict__ Wih0, const float* __restrict__ Whh0,
                  const float* __restrict__ bih0, const float* __restrict__ bhh0,
                  const float* __restrict__ Wih1, const float* __restrict__ Whh1,
                  const float* __restrict__ bih1, const float* __restrict__ bhh1,
                  ushort* __restrict__ y /* bf16 bits, flat [T,B,H] */) {
    const int l     = threadIdx.x;               // 0..63
    const int e_loc = l / 10;                    // 0..5 real, 6 = lanes 60-63
    const int u     = l - e_loc * 10;            // unit 0..9 (0..3 for e_loc==6)
    const long b    = (long)blockIdx.x * 6 + e_loc;
    const bool active = (e_loc < 6) && (b < BATCH);
    const long b_eff  = (b < BATCH) ? b : (BATCH - 1);   // clamp for loads
    const int shfl_base = e_loc * 10;

    // ---- per-lane weight registers: rows {u, u+10, u+20, u+30} ----
    // Gate g: 0=i,1=f,2=g(tanh),3=o. Sigmoid gates scaled by -1.4427,
    // tanh gate by -2.8854 (folded exp2 argument scaling).
    float wih0[4][2], whh0[4][10], bias0[4];
    float wih1[4][10], whh1[4][10], bias1[4];
#pragma unroll
    for (int g = 0; g < 4; ++g) {
        const float sc = (g == 2) ? TANH_SCALE : SIG_SCALE;
        const int r = u + 10 * g;
        wih0[g][0] = Wih0[r * 2] * sc;
        wih0[g][1] = Wih0[r * 2 + 1] * sc;
        bias0[g]   = (bih0[r] + bhh0[r]) * sc;
        bias1[g]   = (bih1[r] + bhh1[r]) * sc;
#pragma unroll
        for (int k = 0; k < 10; ++k) {
            whh0[g][k] = Whh0[r * 10 + k] * sc;
            wih1[g][k] = Wih1[r * 10 + k] * sc;
            whh1[g][k] = Whh1[r * 10 + k] * sc;
        }
    }
    // Pin every weight in a VGPR: opaque asm defs kill load-rematerialization.
#pragma unroll
    for (int g = 0; g < 4; ++g) {
        asm("" : "+v"(wih0[g][0]), "+v"(wih0[g][1]), "+v"(bias0[g]), "+v"(bias1[g]));
#pragma unroll
        for (int k = 0; k < 10; ++k) {
            asm("" : "+v"(whh0[g][k]), "+v"(wih1[g][k]), "+v"(whh1[g][k]));
        }
    }

    // ---- state (loads clamped, stores guarded) ----
    float h0b[10], h1b[10], c0r, c1r;
#pragma unroll
    for (int k = 0; k < 10; ++k) {
        h0b[k] = h0in[b_eff * 10 + k];
        h1b[k] = h0in[(size_t)BATCH * 10 + b_eff * 10 + k];
    }
    c0r = c0in[b_eff * 10 + u];
    c1r = c0in[(size_t)BATCH * 10 + b_eff * 10 + u];

    float2 xv = *reinterpret_cast<const float2*>(&x[b_eff * 2]);

    for (int t = 0; t < SEQ; ++t) {
        const int tn = (t + 1 < SEQ) ? (t + 1) : t;
        const float2 xnext = *reinterpret_cast<const float2*>(&x[((size_t)tn * BATCH + b_eff) * 2]);

        // ----- layer 0 -----
        float a[4];
#pragma unroll
        for (int g = 0; g < 4; ++g)
            a[g] = bias0[g] + wih0[g][0] * xv.x + wih0[g][1] * xv.y;
#pragma unroll
        for (int k = 0; k < 10; ++k) {
#pragma unroll
            for (int g = 0; g < 4; ++g) a[g] += whh0[g][k] * h0b[k];
        }
        const float i0 = sig_pre(a[0]);
        const float f0 = sig_pre(a[1]);
        const float g0 = tanh_pre(a[2]);
        const float o0 = sig_pre(a[3]);
        c0r = f0 * c0r + i0 * g0;
        const float h0n = o0 * fast_tanh(c0r);
#pragma unroll
        for (int k = 0; k < 10; ++k) h0b[k] = __shfl(h0n, shfl_base + k, 64);

        // ----- layer 1 -----
#pragma unroll
        for (int g = 0; g < 4; ++g) a[g] = bias1[g];
#pragma unroll
        for (int k = 0; k < 10; ++k) {
#pragma unroll
            for (int g = 0; g < 4; ++g)
                a[g] += wih1[g][k] * h0b[k] + whh1[g][k] * h1b[k];
        }
        const float i1 = sig_pre(a[0]);
        const float f1 = sig_pre(a[1]);
        const float g1 = tanh_pre(a[2]);
        const float o1 = sig_pre(a[3]);
        c1r = f1 * c1r + i1 * g1;
        const float h1n = o1 * fast_tanh(c1r);
#pragma unroll
        for (int k = 0; k < 10; ++k) h1b[k] = __shfl(h1n, shfl_base + k, 64);

        if (active) y[(size_t)t * BATCH * HID + b * 10 + u] = bf16bits(fast_tanh(h1n));
        xv = xnext;
    }
}

// Head: row b of tanh(y1).view(B,-1) is the contiguous flat range [b*800,(b+1)*800).
// 4 lanes per row, each dotting 200 contiguous bf16 elements, butterfly-reduced.
__global__ __launch_bounds__(256)
void head_kernel(const ushort* __restrict__ yflat, /* bf16 bits, 80*32768*10 */
                 const float* __restrict__ W1, const float* __restrict__ b1,
                 const float* __restrict__ W2, const float* __restrict__ b2,
                 float* __restrict__ out) {
    const int tid = blockIdx.x * blockDim.x + threadIdx.x;
    const int row = tid >> 2;
    const int sub = tid & 3;
    if (row >= BATCH) return;

    const ushort* yr = yflat + (size_t)row * 800 + sub * 200;
    const int kbase = sub * 200;
    float acc[10];
#pragma unroll
    for (int o = 0; o < 10; ++o) acc[o] = 0.f;

#pragma unroll 2
    for (int k0 = 0; k0 < 200; k0 += 8) {
        const uint4 q = *reinterpret_cast<const uint4*>(yr + k0);  // 16B aligned
        float yv[8];
        yv[0] = __uint_as_float(q.x << 16); yv[1] = __uint_as_float(q.x & 0xffff0000u);
        yv[2] = __uint_as_float(q.y << 16); yv[3] = __uint_as_float(q.y & 0xffff0000u);
        yv[4] = __uint_as_float(q.z << 16); yv[5] = __uint_as_float(q.z & 0xffff0000u);
        yv[6] = __uint_as_float(q.w << 16); yv[7] = __uint_as_float(q.w & 0xffff0000u);
#pragma unroll
        for (int uu = 0; uu < 8; ++uu) {
#pragma unroll
            for (int o = 0; o < 10; ++o) acc[o] += yv[uu] * W1[o * 800 + kbase + k0 + uu];
        }
    }

    // butterfly reduce across the 4 sub-lanes
#pragma unroll
    for (int o = 0; o < 10; ++o) {
        acc[o] += __shfl_xor(acc[o], 1, 64);
        acc[o] += __shfl_xor(acc[o], 2, 64);
    }

    float s[10];
#pragma unroll
    for (int o = 0; o < 10; ++o) s[o] = __builtin_amdgcn_rcpf(1.0f + __builtin_amdgcn_exp2f(-1.44269504f * (acc[o] + b1[o])));

    // each sub-lane produces 10 of the 40 outputs
    const int jbase = sub * 10;
#pragma unroll
    for (int jj = 0; jj < 10; ++jj) {
        const int j = jbase + jj;
        float r = b2[j];
#pragma unroll
        for (int o = 0; o < 10; ++o) r += s[o] * W2[j * 10 + o];
        out[(size_t)row * 40 + j] = r;
    }
}

extern "C" void kernel_launch(void* const* d_in, const int* in_sizes, int n_in,
                              void* d_out, int out_size, void* d_ws, size_t ws_size,
                              hipStream_t stream) {
    const float* x    = (const float*)d_in[0];
    const float* h0   = (const float*)d_in[1];
    const float* c0   = (const float*)d_in[2];
    const float* Wih0 = (const float*)d_in[3];
    const float* Whh0 = (const float*)d_in[4];
    const float* bih0 = (const float*)d_in[5];
    const float* bhh0 = (const float*)d_in[6];
    const float* Wih1 = (const float*)d_in[7];
    const float* Whh1 = (const float*)d_in[8];
    const float* bih1 = (const float*)d_in[9];
    const float* bhh1 = (const float*)d_in[10];
    const float* W1   = (const float*)d_in[11];
    const float* b1   = (const float*)d_in[12];
    const float* W2   = (const float*)d_in[13];
    const float* b2   = (const float*)d_in[14];
    float* out = (float*)d_out;
    ushort* yws = (ushort*)d_ws;  // bf16 staging, 80*32768*10*2 = 52,428,800 bytes

    // 6 batch elements per 64-thread (1-wave) block
    const int grid_lstm = (BATCH + 5) / 6;   // 5462
    lstm2_kernel<<<grid_lstm, 64, 0, stream>>>(x, h0, c0, Wih0, Whh0, bih0, bhh0,
                                               Wih1, Whh1, bih1, bhh1, yws);
    head_kernel<<<(BATCH * 4) / 256, 256, 0, stream>>>(yws, W1, b1, W2, b2, out);
}